// Round 6
// baseline (418.974 us; speedup 1.0000x reference)
//
#include <hip/hip_runtime.h>
#include <math.h>

// x: (4,16,256,32,64) f32 -> NS=64 samples, CD=256 channels, HW=2048 positions
#define NS 64
#define CD 256
#define HW 2048
#define MD 1024
#define SAMPLE (CD * HW)
#define LN_EPS 1e-5f

#define PB 64            // positions per block
#define MC 128           // m-chunk
#define NCHUNK (MD / MC) // 8

typedef float f32x4 __attribute__((ext_vector_type(4)));
typedef long i64;

// Rotated 4-bit XOR swizzle. k = 4-bit row key (bijective over p&15).
// Byte-offset XOR = ((k&7)<<4) | (k&8): bank-pair index of a b64 access
// becomes (q>>3) ^ rotl1(k) -- a permutation over 16 lanes -> 16 distinct
// bank pairs -> zero read conflicts. Keeps 8-byte alignment (bits 0-2 clear).
__device__ __forceinline__ int swz(int p) {
  int k = (p ^ (p >> 2)) & 15;
  return ((k & 7) << 4) | (k & 8);
}

// ---------------- weight prep: f32 -> fp8 e4m3, transposed ----------------
__global__ __launch_bounds__(256) void k_prep(const float* __restrict__ w_in,
                                              const float* __restrict__ w_out,
                                              unsigned char* __restrict__ w_in8,
                                              unsigned char* __restrict__ w_out8) {
  int id = blockIdx.x * 256 + threadIdx.x;  // 0..131071
  if (id < 65536) {
    int m = id >> 6, c0 = (id & 63) * 4;
    float a = w_in[(size_t)(c0 + 0) * MD + m];
    float b = w_in[(size_t)(c0 + 1) * MD + m];
    float c = w_in[(size_t)(c0 + 2) * MD + m];
    float d = w_in[(size_t)(c0 + 3) * MD + m];
    int r = __builtin_amdgcn_cvt_pk_fp8_f32(a, b, 0, false);
    r = __builtin_amdgcn_cvt_pk_fp8_f32(c, d, r, true);
    ((int*)w_in8)[id] = r;  // [m][c]
  } else {
    int j = id - 65536;
    int c = j >> 8, m0 = (j & 255) * 4;
    float a = w_out[(size_t)(m0 + 0) * CD + c];
    float b = w_out[(size_t)(m0 + 1) * CD + c];
    float cc = w_out[(size_t)(m0 + 2) * CD + c];
    float d = w_out[(size_t)(m0 + 3) * CD + c];
    int r = __builtin_amdgcn_cvt_pk_fp8_f32(a, b, 0, false);
    r = __builtin_amdgcn_cvt_pk_fp8_f32(cc, d, r, true);
    ((int*)w_out8)[j] = r;  // [c][m]
  }
}

// ---------------- LN stats, stage 1 ----------------
__global__ __launch_bounds__(256) void k_stats1(const float* __restrict__ x,
                                                double* __restrict__ partial) {
  int s = blockIdx.x >> 3, sl = blockIdx.x & 7;
  const float4* p = (const float4*)(x + (size_t)s * SAMPLE + (size_t)sl * 65536);
  double sum = 0.0, ssq = 0.0;
  for (int i = 0; i < 64; ++i) {
    float4 v = p[i * 256 + threadIdx.x];
    sum += (double)v.x + (double)v.y + (double)v.z + (double)v.w;
    ssq += (double)v.x * v.x + (double)v.y * v.y + (double)v.z * v.z + (double)v.w * v.w;
  }
  for (int off = 32; off; off >>= 1) {
    sum += __shfl_down(sum, off);
    ssq += __shfl_down(ssq, off);
  }
  __shared__ double red[4][2];
  int wv = threadIdx.x >> 6, ln = threadIdx.x & 63;
  if (ln == 0) { red[wv][0] = sum; red[wv][1] = ssq; }
  __syncthreads();
  if (threadIdx.x == 0) {
    for (int i = 1; i < 4; ++i) { sum += red[i][0]; ssq += red[i][1]; }
    partial[blockIdx.x * 2] = sum;
    partial[blockIdx.x * 2 + 1] = ssq;
  }
}

// ---------------- LN stats, stage 2 ----------------
__global__ void k_stats2(const double* __restrict__ partial, float* __restrict__ stats) {
  int s = threadIdx.x;  // 64 threads
  double sum = 0.0, ssq = 0.0;
  for (int i = 0; i < 8; ++i) {
    sum += partial[(s * 8 + i) * 2];
    ssq += partial[(s * 8 + i) * 2 + 1];
  }
  double mean = sum / (double)SAMPLE;
  double var = ssq / (double)SAMPLE - mean * mean;
  stats[s * 2] = (float)mean;
  stats[s * 2 + 1] = (float)(1.0 / sqrt(var + (double)LN_EPS));
}

// ---------------- fused LN + MLP + layer-scale + residual ----------------
// r3 loop structure (GEMM1 -> GELU -> barrier -> GEMM2; 1 barrier/chunk; no
// breg cache -- it spilled in r4/r5). New: (a) rotated 4-bit swizzle (0-conflict
// b64 reads); (b) GEMM1 waves = 4 m-groups x 2 p-halves, 32m x 32p each:
// Ysh reads halved (B-frags shared across 2 A-frags); (c) Tsh flat [64][256]
// with dbuf bit folded into the swizzled byte (full-row bank spread).
__global__ __launch_bounds__(512, 4) void k_fused(
    const float* __restrict__ x, const float* __restrict__ ln_w, const float* __restrict__ ln_b,
    const float* __restrict__ b_in, const float* __restrict__ b_out, const float* __restrict__ gamma,
    const unsigned char* __restrict__ w_in8, const unsigned char* __restrict__ w_out8,
    const float* __restrict__ stats, float* __restrict__ out) {
  __shared__ unsigned char Ysh[64 * 256];   // [p][c] fp8, swizzled
  __shared__ unsigned char Tsh[64 * 256];   // [p][dbuf|m] fp8, swizzled

  const int tid = threadIdx.x;
  const int s = blockIdx.x >> 5;
  const int p0 = (blockIdx.x & 31) * PB;
  const float mu = stats[s * 2], rstd = stats[s * 2 + 1];
  const float a_ln = rstd, c_ln = -mu * rstd;
  const size_t xbase = (size_t)s * SAMPLE;

  // ---- stage Ysh: normalize + affine, transpose (c,p)->(p,c), cvt fp8 ----
  #pragma unroll
  for (int it = 0; it < 2; ++it) {
    int bid = it * 512 + tid;               // 1024 4x4 micro-blocks
    int c0 = (bid >> 4) * 4, pp = (bid & 15) * 4;
    float yv[4][4];
    #pragma unroll
    for (int i = 0; i < 4; ++i) {
      size_t off = (size_t)(c0 + i) * HW + p0 + pp;
      float4 xv = *(const float4*)(x + xbase + off);
      float4 lw = *(const float4*)(ln_w + off);
      float4 lb = *(const float4*)(ln_b + off);
      yv[i][0] = fmaf(fmaf(xv.x, a_ln, c_ln), lw.x, lb.x);
      yv[i][1] = fmaf(fmaf(xv.y, a_ln, c_ln), lw.y, lb.y);
      yv[i][2] = fmaf(fmaf(xv.z, a_ln, c_ln), lw.z, lb.z);
      yv[i][3] = fmaf(fmaf(xv.w, a_ln, c_ln), lw.w, lb.w);
    }
    #pragma unroll
    for (int j = 0; j < 4; ++j) {
      int p = pp + j;
      int r = __builtin_amdgcn_cvt_pk_fp8_f32(yv[0][j], yv[1][j], 0, false);
      r = __builtin_amdgcn_cvt_pk_fp8_f32(yv[2][j], yv[3][j], r, true);
      *(int*)&Ysh[p * 256 + (c0 ^ swz(p))] = r;
    }
  }

  const int lane = tid & 63, l15 = lane & 15, l4 = lane >> 4;
  const int w = tid >> 6;
  const int mg = w & 3, ph = w >> 2;   // GEMM1: m-group 32*mg, p-half 32*ph

  f32x4 acc2[4][2] = {};  // 64p x 32c per wave, persistent

  __syncthreads();  // Ysh ready (immutable hereafter)

  const unsigned char* A0 = w_in8 + (size_t)(32 * mg + l15) * CD + l4 * 8;
  const unsigned char* Brow = w_out8 + (size_t)(32 * w + l15) * MD + l4 * 8;
  const int pA = ph * 32 + l15, pB = pA + 16;
  const int sA = swz(pA), sB = swz(pB);

  for (int ch = 0; ch < NCHUNK; ++ch) {
    const int m0 = ch * MC;
    const int buf = (ch & 1) << 7;

    // ---- GEMM1(ch): D1[m][p], wave slice 32m x 32p, K=256 ----
    f32x4 acc1[2][2] = {};
    #pragma unroll
    for (int kk = 0; kk < 8; ++kk) {
      i64 a0 = *(const i64*)(A0 + (size_t)m0 * CD + kk * 32);
      i64 a1 = *(const i64*)(A0 + (size_t)(m0 + 16) * CD + kk * 32);
      i64 b0 = *(const i64*)&Ysh[pA * 256 + ((kk * 32 + l4 * 8) ^ sA)];
      i64 b1 = *(const i64*)&Ysh[pB * 256 + ((kk * 32 + l4 * 8) ^ sB)];
      acc1[0][0] = __builtin_amdgcn_mfma_f32_16x16x32_fp8_fp8(a0, b0, acc1[0][0], 0, 0, 0);
      acc1[0][1] = __builtin_amdgcn_mfma_f32_16x16x32_fp8_fp8(a0, b1, acc1[0][1], 0, 0, 0);
      acc1[1][0] = __builtin_amdgcn_mfma_f32_16x16x32_fp8_fp8(a1, b0, acc1[1][0], 0, 0, 0);
      acc1[1][1] = __builtin_amdgcn_mfma_f32_16x16x32_fp8_fp8(a1, b1, acc1[1][1], 0, 0, 0);
    }

    // ---- epilogue1(ch): +b_in, sigmoid-GELU, pack fp8 -> Tsh[p][buf|m] ----
    #pragma unroll
    for (int mi = 0; mi < 2; ++mi) {
      const int mcol = 32 * mg + 16 * mi + 4 * l4;
      const float4 bi = *(const float4*)&b_in[m0 + mcol];
      #pragma unroll
      for (int pi = 0; pi < 2; ++pi) {
        int p = 32 * ph + 16 * pi + l15;
        float g[4];
        #pragma unroll
        for (int r = 0; r < 4; ++r) {
          float t = acc1[mi][pi][r] + ((const float*)&bi)[r];
          g[r] = t * __builtin_amdgcn_rcpf(1.0f + __expf(-1.702f * t));
        }
        int pk = __builtin_amdgcn_cvt_pk_fp8_f32(g[0], g[1], 0, false);
        pk = __builtin_amdgcn_cvt_pk_fp8_f32(g[2], g[3], pk, true);
        *(int*)&Tsh[p * 256 + ((buf | mcol) ^ swz(p))] = pk;
      }
    }

    // ---- b2 (GEMM2 B-frags) from global; L2 latency overlaps barrier wait ----
    i64 b2a[4], b2b[4];
    #pragma unroll
    for (int kk = 0; kk < 4; ++kk) {
      b2a[kk] = *(const i64*)(Brow + m0 + kk * 32);
      b2b[kk] = *(const i64*)(Brow + (size_t)16 * MD + m0 + kk * 32);
    }

    __syncthreads();  // T(ch) ready

    // ---- GEMM2(ch): acc2 += T (64p x 128m) x w_out chunk; 64p x 32c/wave ----
    #pragma unroll
    for (int kk = 0; kk < 4; ++kk) {
      i64 a2[4];
      #pragma unroll
      for (int mi = 0; mi < 4; ++mi) {
        int p = mi * 16 + l15;
        a2[mi] = *(const i64*)&Tsh[p * 256 + ((buf | (kk * 32 + l4 * 8)) ^ swz(p))];
      }
      #pragma unroll
      for (int mi = 0; mi < 4; ++mi) {
        acc2[mi][0] = __builtin_amdgcn_mfma_f32_16x16x32_fp8_fp8(a2[mi], b2a[kk], acc2[mi][0], 0, 0, 0);
        acc2[mi][1] = __builtin_amdgcn_mfma_f32_16x16x32_fp8_fp8(a2[mi], b2b[kk], acc2[mi][1], 0, 0, 0);
      }
    }
  }

  // ---- epilogue: out = x + gamma_c * (v + b_out_c) ----
  #pragma unroll
  for (int ni = 0; ni < 2; ++ni) {
    int cc = 32 * w + 16 * ni + l15;
    float gm = gamma[cc], bo = b_out[cc];
    #pragma unroll
    for (int mi = 0; mi < 4; ++mi) {
      int p = p0 + 16 * mi + 4 * l4;
      size_t off = xbase + (size_t)cc * HW + p;
      float4 xv = *(const float4*)(x + off);
      float4 o;
      #pragma unroll
      for (int r = 0; r < 4; ++r)
        ((float*)&o)[r] = ((const float*)&xv)[r] + gm * (acc2[mi][ni][r] + bo);
      *(float4*)(out + off) = o;
    }
  }
}

extern "C" void kernel_launch(void* const* d_in, const int* in_sizes, int n_in,
                              void* d_out, int out_size, void* d_ws, size_t ws_size,
                              hipStream_t stream) {
  const float* x = (const float*)d_in[0];
  const float* ln_w = (const float*)d_in[1];
  const float* ln_b = (const float*)d_in[2];
  const float* w_in = (const float*)d_in[3];
  const float* b_in = (const float*)d_in[4];
  const float* w_out = (const float*)d_in[5];
  const float* b_out = (const float*)d_in[6];
  const float* gamma = (const float*)d_in[7];
  float* out = (float*)d_out;

  char* ws = (char*)d_ws;
  unsigned char* w_in8 = (unsigned char*)ws;              // 256 KB [m][c]
  unsigned char* w_out8 = (unsigned char*)(ws + 262144);  // 256 KB [c][m]
  double* partial = (double*)(ws + 524288);               // 8 KB
  float* stats = (float*)(ws + 524288 + 8192);            // 512 B

  k_prep<<<512, 256, 0, stream>>>(w_in, w_out, w_in8, w_out8);
  k_stats1<<<512, 256, 0, stream>>>(x, partial);
  k_stats2<<<1, 64, 0, stream>>>(partial, stats);

  k_fused<<<2048, 512, 0, stream>>>(x, ln_w, ln_b, b_in, b_out, gamma,
                                    w_in8, w_out8, stats, out);
}

// Round 8
// 209.294 us; speedup vs baseline: 2.0018x; 2.0018x over previous
//
#include <hip/hip_runtime.h>
#include <math.h>

// x: (4,16,256,32,64) f32 -> NS=64 samples, CD=256 channels, HW=2048 positions
#define NS 64
#define CD 256
#define HW 2048
#define MD 1024
#define SAMPLE (CD * HW)
#define LN_EPS 1e-5f

#define PB 64            // positions per block (4 waves x 16-p strip)
#define MC 32            // m-chunk
#define NCH (MD / MC)    // 32 chunks

typedef float f32x4 __attribute__((ext_vector_type(4)));
typedef long i64;

// Rotated 4-bit XOR swizzle for Ysh (bits 3-6), r6-verified balanced.
__device__ __forceinline__ int swz(int p) {
  int k = (p ^ (p >> 2)) & 15;
  return ((k & 7) << 4) | (k & 8);
}

__device__ __forceinline__ void gl_lds16(const unsigned char* g, unsigned char* l) {
  __builtin_amdgcn_global_load_lds(
      (const __attribute__((address_space(1))) unsigned char*)g,
      (__attribute__((address_space(3))) unsigned char*)l, 16, 0, 0);
}

// ---------------- weight prep: f32 -> fp8 e4m3, FRAGMENT-PACKED ----------------
// w_in8p[f*512 + l*8 + j]  = w_in[c,m], f=(ch*16)+mt*8+kk, m=ch*32+mt*16+(l&15),
//                            c=kk*32+(l>>4)*8+j
// w_out8p[g*512 + l*8 + j] = w_out[m,c], g=(ch*16)+ct, c=ct*16+(l&15),
//                            m=ch*32+(l>>4)*8+j
__global__ __launch_bounds__(256) void k_prep(const float* __restrict__ w_in,
                                              const float* __restrict__ w_out,
                                              unsigned char* __restrict__ w_in8p,
                                              unsigned char* __restrict__ w_out8p) {
  int id = blockIdx.x * 256 + threadIdx.x;  // 0..131071 (one int = 4 bytes each)
  if (id < 65536) {
    int i = id;
    int f = i >> 7, l = (i >> 1) & 63, j0 = (i & 1) * 4;
    int m = (f >> 3) * 16 + (l & 15);
    int c0 = (f & 7) * 32 + (l >> 4) * 8 + j0;
    float a = w_in[(size_t)(c0 + 0) * MD + m];
    float b = w_in[(size_t)(c0 + 1) * MD + m];
    float c = w_in[(size_t)(c0 + 2) * MD + m];
    float d = w_in[(size_t)(c0 + 3) * MD + m];
    int r = __builtin_amdgcn_cvt_pk_fp8_f32(a, b, 0, false);
    r = __builtin_amdgcn_cvt_pk_fp8_f32(c, d, r, true);
    ((int*)w_in8p)[i] = r;
  } else {
    int i = id - 65536;
    int g = i >> 7, l = (i >> 1) & 63, j0 = (i & 1) * 4;
    int c = (g & 15) * 16 + (l & 15);
    int m0 = (g >> 4) * 32 + (l >> 4) * 8 + j0;
    float a = w_out[(size_t)(m0 + 0) * CD + c];
    float b = w_out[(size_t)(m0 + 1) * CD + c];
    float cc = w_out[(size_t)(m0 + 2) * CD + c];
    float d = w_out[(size_t)(m0 + 3) * CD + c];
    int r = __builtin_amdgcn_cvt_pk_fp8_f32(a, b, 0, false);
    r = __builtin_amdgcn_cvt_pk_fp8_f32(cc, d, r, true);
    ((int*)w_out8p)[i] = r;
  }
}

// ---------------- LN stats, stage 1 ----------------
__global__ __launch_bounds__(256) void k_stats1(const float* __restrict__ x,
                                                double* __restrict__ partial) {
  int s = blockIdx.x >> 3, sl = blockIdx.x & 7;
  const float4* p = (const float4*)(x + (size_t)s * SAMPLE + (size_t)sl * 65536);
  double sum = 0.0, ssq = 0.0;
  for (int i = 0; i < 64; ++i) {
    float4 v = p[i * 256 + threadIdx.x];
    sum += (double)v.x + (double)v.y + (double)v.z + (double)v.w;
    ssq += (double)v.x * v.x + (double)v.y * v.y + (double)v.z * v.z + (double)v.w * v.w;
  }
  for (int off = 32; off; off >>= 1) {
    sum += __shfl_down(sum, off);
    ssq += __shfl_down(ssq, off);
  }
  __shared__ double red[4][2];
  int wv = threadIdx.x >> 6, ln = threadIdx.x & 63;
  if (ln == 0) { red[wv][0] = sum; red[wv][1] = ssq; }
  __syncthreads();
  if (threadIdx.x == 0) {
    for (int i = 1; i < 4; ++i) { sum += red[i][0]; ssq += red[i][1]; }
    partial[blockIdx.x * 2] = sum;
    partial[blockIdx.x * 2 + 1] = ssq;
  }
}

// ---------------- LN stats, stage 2 ----------------
__global__ void k_stats2(const double* __restrict__ partial, float* __restrict__ stats) {
  int s = threadIdx.x;  // 64 threads
  double sum = 0.0, ssq = 0.0;
  for (int i = 0; i < 8; ++i) {
    sum += partial[(s * 8 + i) * 2];
    ssq += partial[(s * 8 + i) * 2 + 1];
  }
  double mean = sum / (double)SAMPLE;
  double var = ssq / (double)SAMPLE - mean * mean;
  stats[s * 2] = (float)mean;
  stats[s * 2 + 1] = (float)(1.0 / sqrt(var + (double)LN_EPS));
}

// ---------------- fused LN + MLP + layer-scale + residual ----------------
// 256 thr / 4 waves, PB=64: wave owns a 16-p strip end-to-end. GELU output is
// transposed to GEMM2 A-frag layout IN REGISTERS (4 __shfl + 2 selects) -- no
// LDS scratch, no write->read ordering hazard (r7's NaN: type-punned LDS RAW
// with no barrier let TBAA reorder the read before the write). Weights are
// fragment-packed and staged via global_load_lds into dbuf LDS one chunk
// ahead; all weight LDS reads lane-linear. One barrier per chunk.
__global__ __launch_bounds__(256, 3) void k_fused(
    const float* __restrict__ x, const float* __restrict__ ln_w, const float* __restrict__ ln_b,
    const float* __restrict__ b_in, const float* __restrict__ b_out, const float* __restrict__ gamma,
    const unsigned char* __restrict__ w_in8p, const unsigned char* __restrict__ w_out8p,
    const float* __restrict__ stats, float* __restrict__ out) {
  __shared__ unsigned char Ysh[64 * 256];      // [p][c] fp8 swizzled, 16KB
  __shared__ unsigned char Wsh1[2][16 * 512];  // 16 a-frags/chunk, 2x8KB
  __shared__ unsigned char Wsh2[2][16 * 512];  // 16 b2-frags/chunk, 2x8KB

  const int tid = threadIdx.x;
  const int lane = tid & 63, l15 = lane & 15, l4 = lane >> 4;
  const int wv = tid >> 6;
  const int s = blockIdx.x >> 5;
  const int p0 = (blockIdx.x & 31) * PB;
  const float mu = stats[s * 2], rstd = stats[s * 2 + 1];
  const float a_ln = rstd, c_ln = -mu * rstd;
  const size_t xbase = (size_t)s * SAMPLE;

  // ---- prefetch chunk 0 weights (hides under Ysh staging) ----
  {
    const int sl0 = wv, sl1 = wv + 4;  // two 1KB slices per wave per buffer
    gl_lds16(w_in8p + sl0 * 1024 + lane * 16, &Wsh1[0][sl0 * 1024]);
    gl_lds16(w_in8p + sl1 * 1024 + lane * 16, &Wsh1[0][sl1 * 1024]);
    gl_lds16(w_out8p + sl0 * 1024 + lane * 16, &Wsh2[0][sl0 * 1024]);
    gl_lds16(w_out8p + sl1 * 1024 + lane * 16, &Wsh2[0][sl1 * 1024]);
  }

  // ---- stage Ysh: normalize + affine, transpose (c,p)->(p,c), cvt fp8 ----
  #pragma unroll
  for (int it = 0; it < 4; ++it) {
    int bid = it * 256 + tid;               // 1024 4x4 micro-blocks
    int c0 = (bid >> 4) * 4, pp = (bid & 15) * 4;
    float yv[4][4];
    #pragma unroll
    for (int i = 0; i < 4; ++i) {
      size_t off = (size_t)(c0 + i) * HW + p0 + pp;
      float4 xv = *(const float4*)(x + xbase + off);
      float4 lw = *(const float4*)(ln_w + off);
      float4 lb = *(const float4*)(ln_b + off);
      yv[i][0] = fmaf(fmaf(xv.x, a_ln, c_ln), lw.x, lb.x);
      yv[i][1] = fmaf(fmaf(xv.y, a_ln, c_ln), lw.y, lb.y);
      yv[i][2] = fmaf(fmaf(xv.z, a_ln, c_ln), lw.z, lb.z);
      yv[i][3] = fmaf(fmaf(xv.w, a_ln, c_ln), lw.w, lb.w);
    }
    #pragma unroll
    for (int j = 0; j < 4; ++j) {
      int p = pp + j;
      int r = __builtin_amdgcn_cvt_pk_fp8_f32(yv[0][j], yv[1][j], 0, false);
      r = __builtin_amdgcn_cvt_pk_fp8_f32(yv[2][j], yv[3][j], r, true);
      *(int*)&Ysh[p * 256 + (c0 ^ swz(p))] = r;
    }
  }

  const int strip = wv * 16;               // wave's p-strip
  const int pY = strip + l15;              // Ysh row this lane reads
  const int sY = swz(pY);
  f32x4 acc2[16] = {};                     // 16p x 256c per wave (16 c-tiles)

  __syncthreads();  // Ysh ready + Wsh buf0 ready (vmcnt drained before barrier)

  for (int ch = 0; ch < NCH; ++ch) {
    const int b = ch & 1;

    // ---- prefetch chunk ch+1 into buf b^1 (full chunk to complete) ----
    if (ch + 1 < NCH) {
      const size_t co = (size_t)(ch + 1) * 8192;
      const int sl0 = wv, sl1 = wv + 4;
      gl_lds16(w_in8p + co + sl0 * 1024 + lane * 16, &Wsh1[b ^ 1][sl0 * 1024]);
      gl_lds16(w_in8p + co + sl1 * 1024 + lane * 16, &Wsh1[b ^ 1][sl1 * 1024]);
      gl_lds16(w_out8p + co + sl0 * 1024 + lane * 16, &Wsh2[b ^ 1][sl0 * 1024]);
      gl_lds16(w_out8p + co + sl1 * 1024 + lane * 16, &Wsh2[b ^ 1][sl1 * 1024]);
    }

    // ---- GEMM1(ch): D1[32m x 16p], K=256; a-frags lane-linear from Wsh1 ----
    const unsigned char* W1 = Wsh1[b];
    f32x4 acc1[2] = {};
    #pragma unroll
    for (int kk = 0; kk < 8; ++kk) {
      i64 bf = *(const i64*)&Ysh[pY * 256 + ((kk * 32 + l4 * 8) ^ sY)];
      i64 a0 = *(const i64*)&W1[(kk)*512 + lane * 8];
      i64 a1 = *(const i64*)&W1[(8 + kk) * 512 + lane * 8];
      acc1[0] = __builtin_amdgcn_mfma_f32_16x16x32_fp8_fp8(a0, bf, acc1[0], 0, 0, 0);
      acc1[1] = __builtin_amdgcn_mfma_f32_16x16x32_fp8_fp8(a1, bf, acc1[1], 0, 0, 0);
    }

    // ---- GELU -> packed fp8 ints (per mt block), all in registers ----
    int pk0, pk1;
    #pragma unroll
    for (int mt = 0; mt < 2; ++mt) {
      const float4 bi = *(const float4*)&b_in[ch * 32 + mt * 16 + l4 * 4];
      float g[4];
      #pragma unroll
      for (int r = 0; r < 4; ++r) {
        float t = acc1[mt][r] + ((const float*)&bi)[r];
        g[r] = t * __builtin_amdgcn_rcpf(1.0f + __expf(-1.702f * t));
      }
      int pk = __builtin_amdgcn_cvt_pk_fp8_f32(g[0], g[1], 0, false);
      pk = __builtin_amdgcn_cvt_pk_fp8_f32(g[2], g[3], pk, true);
      if (mt == 0) pk0 = pk; else pk1 = pk;
    }

    // ---- in-register transpose to GEMM2 A-frag layout (4 shfl, no LDS) ----
    // writer lane (l15,l4w) holds pk_mt = T[p=strip+l15][m=mt*16+l4w*4..+3];
    // reader lane (l15,l4) needs m = 8*l4+j, j=0..7:
    //   lo int (j=0..3): src lane l15+32*(l4&1),    val pk[l4>>1]
    //   hi int (j=4..7): src lane l15+32*(l4&1)+16, val pk[l4>>1]
    {
      const int sl = l15 + 32 * (l4 & 1);
      int v0a = __shfl(pk0, sl), v0b = __shfl(pk1, sl);
      int v1a = __shfl(pk0, sl + 16), v1b = __shfl(pk1, sl + 16);
      int vlo = (l4 & 2) ? v0b : v0a;
      int vhi = (l4 & 2) ? v1b : v1a;
      i64 a2 = (i64)((((unsigned long long)(unsigned)vhi) << 32) | (unsigned)vlo);

      // ---- GEMM2(ch): acc2 += T[16p x 32m] x w_out chunk; K=32 ----
      const unsigned char* W2 = Wsh2[b];
      #pragma unroll
      for (int ct = 0; ct < 16; ++ct) {
        i64 b2 = *(const i64*)&W2[ct * 512 + lane * 8];
        acc2[ct] = __builtin_amdgcn_mfma_f32_16x16x32_fp8_fp8(a2, b2, acc2[ct], 0, 0, 0);
      }
    }

    __syncthreads();  // buf flip: prefetch(ch+1) drained; all waves done with buf b
  }

  // ---- epilogue: out = x + gamma_c * (v + b_out_c) ----
  #pragma unroll
  for (int ct = 0; ct < 16; ++ct) {
    int cc = ct * 16 + l15;
    float gm = gamma[cc], bo = b_out[cc];
    int p = p0 + strip + l4 * 4;
    size_t off = xbase + (size_t)cc * HW + p;
    float4 xv = *(const float4*)(x + off);
    float4 o;
    #pragma unroll
    for (int r = 0; r < 4; ++r)
      ((float*)&o)[r] = ((const float*)&xv)[r] + gm * (acc2[ct][r] + bo);
    *(float4*)(out + off) = o;
  }
}

extern "C" void kernel_launch(void* const* d_in, const int* in_sizes, int n_in,
                              void* d_out, int out_size, void* d_ws, size_t ws_size,
                              hipStream_t stream) {
  const float* x = (const float*)d_in[0];
  const float* ln_w = (const float*)d_in[1];
  const float* ln_b = (const float*)d_in[2];
  const float* w_in = (const float*)d_in[3];
  const float* b_in = (const float*)d_in[4];
  const float* w_out = (const float*)d_in[5];
  const float* b_out = (const float*)d_in[6];
  const float* gamma = (const float*)d_in[7];
  float* out = (float*)d_out;

  char* ws = (char*)d_ws;
  unsigned char* w_in8p = (unsigned char*)ws;              // 256 KB frag-packed
  unsigned char* w_out8p = (unsigned char*)(ws + 262144);  // 256 KB frag-packed
  double* partial = (double*)(ws + 524288);                // 8 KB
  float* stats = (float*)(ws + 524288 + 8192);             // 512 B

  k_prep<<<512, 256, 0, stream>>>(w_in, w_out, w_in8p, w_out8p);
  k_stats1<<<512, 256, 0, stream>>>(x, partial);
  k_stats2<<<1, 64, 0, stream>>>(partial, stats);

  k_fused<<<2048, 256, 0, stream>>>(x, ln_w, ln_b, b_in, b_out, gamma,
                                    w_in8p, w_out8p, stats, out);
}

// Round 9
// 195.973 us; speedup vs baseline: 2.1379x; 1.0680x over previous
//
#include <hip/hip_runtime.h>
#include <math.h>

// x: (4,16,256,32,64) f32 -> NS=64 samples, CD=256 channels, HW=2048 positions
#define NS 64
#define CD 256
#define HW 2048
#define MD 1024
#define SAMPLE (CD * HW)
#define LN_EPS 1e-5f

#define PB 128           // positions per block (8 waves x 16-p strip)
#define MC 32            // m-chunk
#define NCH (MD / MC)    // 32 chunks

typedef float f32x4 __attribute__((ext_vector_type(4)));
typedef long i64;

// Rotated 4-bit XOR swizzle for Ysh (bits 3-6).
__device__ __forceinline__ int swz(int p) {
  int k = (p ^ (p >> 2)) & 15;
  return ((k & 7) << 4) | (k & 8);
}

__device__ __forceinline__ void gl_lds16(const unsigned char* g, unsigned char* l) {
  __builtin_amdgcn_global_load_lds(
      (const __attribute__((address_space(1))) unsigned char*)g,
      (__attribute__((address_space(3))) unsigned char*)l, 16, 0, 0);
}

// ---------------- weight prep: f32 -> fp8 e4m3, FRAGMENT-PACKED ----------------
// w_in8p[f*512 + l*8 + j]  = w_in[c,m], f=ch*16+mt*8+kk, m=ch*32+mt*16+(l&15),
//                            c=kk*32+(l>>4)*8+j
// w_out8p[g*512 + l*8 + j] = w_out[m,c], g=ch*16+ct, c=ct*16+(l&15),
//                            m=ch*32+(l>>4)*8+j
__global__ __launch_bounds__(256) void k_prep(const float* __restrict__ w_in,
                                              const float* __restrict__ w_out,
                                              unsigned char* __restrict__ w_in8p,
                                              unsigned char* __restrict__ w_out8p) {
  int id = blockIdx.x * 256 + threadIdx.x;  // 0..131071 (one int = 4 bytes each)
  if (id < 65536) {
    int i = id;
    int f = i >> 7, l = (i >> 1) & 63, j0 = (i & 1) * 4;
    int m = (f >> 3) * 16 + (l & 15);
    int c0 = (f & 7) * 32 + (l >> 4) * 8 + j0;
    float a = w_in[(size_t)(c0 + 0) * MD + m];
    float b = w_in[(size_t)(c0 + 1) * MD + m];
    float c = w_in[(size_t)(c0 + 2) * MD + m];
    float d = w_in[(size_t)(c0 + 3) * MD + m];
    int r = __builtin_amdgcn_cvt_pk_fp8_f32(a, b, 0, false);
    r = __builtin_amdgcn_cvt_pk_fp8_f32(c, d, r, true);
    ((int*)w_in8p)[i] = r;
  } else {
    int i = id - 65536;
    int g = i >> 7, l = (i >> 1) & 63, j0 = (i & 1) * 4;
    int c = (g & 15) * 16 + (l & 15);
    int m0 = (g >> 4) * 32 + (l >> 4) * 8 + j0;
    float a = w_out[(size_t)(m0 + 0) * CD + c];
    float b = w_out[(size_t)(m0 + 1) * CD + c];
    float cc = w_out[(size_t)(m0 + 2) * CD + c];
    float d = w_out[(size_t)(m0 + 3) * CD + c];
    int r = __builtin_amdgcn_cvt_pk_fp8_f32(a, b, 0, false);
    r = __builtin_amdgcn_cvt_pk_fp8_f32(cc, d, r, true);
    ((int*)w_out8p)[i] = r;
  }
}

// ---------------- LN stats, stage 1 ----------------
__global__ __launch_bounds__(256) void k_stats1(const float* __restrict__ x,
                                                double* __restrict__ partial) {
  int s = blockIdx.x >> 3, sl = blockIdx.x & 7;
  const float4* p = (const float4*)(x + (size_t)s * SAMPLE + (size_t)sl * 65536);
  double sum = 0.0, ssq = 0.0;
  for (int i = 0; i < 64; ++i) {
    float4 v = p[i * 256 + threadIdx.x];
    sum += (double)v.x + (double)v.y + (double)v.z + (double)v.w;
    ssq += (double)v.x * v.x + (double)v.y * v.y + (double)v.z * v.z + (double)v.w * v.w;
  }
  for (int off = 32; off; off >>= 1) {
    sum += __shfl_down(sum, off);
    ssq += __shfl_down(ssq, off);
  }
  __shared__ double red[4][2];
  int wv = threadIdx.x >> 6, ln = threadIdx.x & 63;
  if (ln == 0) { red[wv][0] = sum; red[wv][1] = ssq; }
  __syncthreads();
  if (threadIdx.x == 0) {
    for (int i = 1; i < 4; ++i) { sum += red[i][0]; ssq += red[i][1]; }
    partial[blockIdx.x * 2] = sum;
    partial[blockIdx.x * 2 + 1] = ssq;
  }
}

// ---------------- LN stats, stage 2 ----------------
__global__ void k_stats2(const double* __restrict__ partial, float* __restrict__ stats) {
  int s = threadIdx.x;  // 64 threads
  double sum = 0.0, ssq = 0.0;
  for (int i = 0; i < 8; ++i) {
    sum += partial[(s * 8 + i) * 2];
    ssq += partial[(s * 8 + i) * 2 + 1];
  }
  double mean = sum / (double)SAMPLE;
  double var = ssq / (double)SAMPLE - mean * mean;
  stats[s * 2] = (float)mean;
  stats[s * 2 + 1] = (float)(1.0 / sqrt(var + (double)LN_EPS));
}

// ---------------- fused LN + MLP + layer-scale + residual ----------------
// 512 thr / 8 waves, PB=128: wave owns a 16-p strip end-to-end. r8 structure
// (register-transposed GELU handoff, frag-packed weights via global_load_lds
// dbuf, 1 barrier/chunk) + two levers:
//  (a) breg: the wave's 8 Ysh B-frags are chunk-invariant -> cached in 16 VGPR
//      (removes 8 b64 LDS reads/chunk AND the Ysh-read latency from GEMM1);
//  (b) PB=128/8-wave: halves staging overhead per position; LDS = 64KB ->
//      2 blocks/CU = 16 waves/CU (vs ~10 in r8) for latency hiding.
__global__ __launch_bounds__(512, 4) void k_fused(
    const float* __restrict__ x, const float* __restrict__ ln_w, const float* __restrict__ ln_b,
    const float* __restrict__ b_in, const float* __restrict__ b_out, const float* __restrict__ gamma,
    const unsigned char* __restrict__ w_in8p, const unsigned char* __restrict__ w_out8p,
    const float* __restrict__ stats, float* __restrict__ out) {
  __shared__ unsigned char Ysh[128 * 256];     // [p][c] fp8 swizzled, 32KB
  __shared__ unsigned char Wsh1[2][16 * 512];  // 16 a-frags/chunk, 2x8KB
  __shared__ unsigned char Wsh2[2][16 * 512];  // 16 b2-frags/chunk, 2x8KB

  const int tid = threadIdx.x;
  const int lane = tid & 63, l15 = lane & 15, l4 = lane >> 4;
  const int wv = tid >> 6;                 // 0..7
  const int s = blockIdx.x >> 4;
  const int p0 = (blockIdx.x & 15) * PB;
  const float mu = stats[s * 2], rstd = stats[s * 2 + 1];
  const float a_ln = rstd, c_ln = -mu * rstd;
  const size_t xbase = (size_t)s * SAMPLE;

  // ---- prefetch chunk 0 weights (hides under Ysh staging) ----
  // 8 waves x 1KB slice each per array.
  gl_lds16(w_in8p + wv * 1024 + lane * 16, &Wsh1[0][wv * 1024]);
  gl_lds16(w_out8p + wv * 1024 + lane * 16, &Wsh2[0][wv * 1024]);

  // ---- stage Ysh: normalize + affine, transpose (c,p)->(p,c), cvt fp8 ----
  #pragma unroll
  for (int it = 0; it < 4; ++it) {
    int bid = it * 512 + tid;               // 2048 4x4 micro-blocks
    int c0 = (bid >> 5) * 4, pp = (bid & 31) * 4;
    float yv[4][4];
    #pragma unroll
    for (int i = 0; i < 4; ++i) {
      size_t off = (size_t)(c0 + i) * HW + p0 + pp;
      float4 xv = *(const float4*)(x + xbase + off);
      float4 lw = *(const float4*)(ln_w + off);
      float4 lb = *(const float4*)(ln_b + off);
      yv[i][0] = fmaf(fmaf(xv.x, a_ln, c_ln), lw.x, lb.x);
      yv[i][1] = fmaf(fmaf(xv.y, a_ln, c_ln), lw.y, lb.y);
      yv[i][2] = fmaf(fmaf(xv.z, a_ln, c_ln), lw.z, lb.z);
      yv[i][3] = fmaf(fmaf(xv.w, a_ln, c_ln), lw.w, lb.w);
    }
    #pragma unroll
    for (int j = 0; j < 4; ++j) {
      int p = pp + j;
      int r = __builtin_amdgcn_cvt_pk_fp8_f32(yv[0][j], yv[1][j], 0, false);
      r = __builtin_amdgcn_cvt_pk_fp8_f32(yv[2][j], yv[3][j], r, true);
      *(int*)&Ysh[p * 256 + (c0 ^ swz(p))] = r;
    }
  }

  const int strip = wv * 16;               // wave's p-strip
  const int pY = strip + l15;              // Ysh row this lane reads
  const int sY = swz(pY);
  f32x4 acc2[16] = {};                     // 16p x 256c per wave (16 c-tiles)

  __syncthreads();  // Ysh ready + Wsh buf0 ready (vmcnt drained before barrier)

  // ---- breg: chunk-invariant Ysh B-frags -> 8 i64 registers ----
  i64 breg[8];
  #pragma unroll
  for (int kk = 0; kk < 8; ++kk)
    breg[kk] = *(const i64*)&Ysh[pY * 256 + ((kk * 32 + l4 * 8) ^ sY)];

  for (int ch = 0; ch < NCH; ++ch) {
    const int b = ch & 1;

    // ---- prefetch chunk ch+1 into buf b^1 (full chunk to complete) ----
    if (ch + 1 < NCH) {
      const size_t co = (size_t)(ch + 1) * 8192;
      gl_lds16(w_in8p + co + wv * 1024 + lane * 16, &Wsh1[b ^ 1][wv * 1024]);
      gl_lds16(w_out8p + co + wv * 1024 + lane * 16, &Wsh2[b ^ 1][wv * 1024]);
    }

    // ---- GEMM1(ch): D1[32m x 16p], K=256; a-frags lane-linear from Wsh1 ----
    const unsigned char* W1 = Wsh1[b];
    f32x4 acc1[2] = {};
    #pragma unroll
    for (int kk = 0; kk < 8; ++kk) {
      i64 a0 = *(const i64*)&W1[(kk)*512 + lane * 8];
      i64 a1 = *(const i64*)&W1[(8 + kk) * 512 + lane * 8];
      acc1[0] = __builtin_amdgcn_mfma_f32_16x16x32_fp8_fp8(a0, breg[kk], acc1[0], 0, 0, 0);
      acc1[1] = __builtin_amdgcn_mfma_f32_16x16x32_fp8_fp8(a1, breg[kk], acc1[1], 0, 0, 0);
    }

    // ---- GELU -> packed fp8 ints (per mt block), all in registers ----
    int pk0, pk1;
    #pragma unroll
    for (int mt = 0; mt < 2; ++mt) {
      const float4 bi = *(const float4*)&b_in[ch * 32 + mt * 16 + l4 * 4];
      float g[4];
      #pragma unroll
      for (int r = 0; r < 4; ++r) {
        float t = acc1[mt][r] + ((const float*)&bi)[r];
        g[r] = t * __builtin_amdgcn_rcpf(1.0f + __expf(-1.702f * t));
      }
      int pk = __builtin_amdgcn_cvt_pk_fp8_f32(g[0], g[1], 0, false);
      pk = __builtin_amdgcn_cvt_pk_fp8_f32(g[2], g[3], pk, true);
      if (mt == 0) pk0 = pk; else pk1 = pk;
    }

    // ---- in-register transpose to GEMM2 A-frag layout (4 shfl, no LDS) ----
    // writer lane (l15,l4w) holds pk_mt = T[p=strip+l15][m=mt*16+l4w*4..+3];
    // reader lane (l15,l4) needs m = 8*l4+j, j=0..7:
    //   lo int (j=0..3): src lane l15+32*(l4&1),    val pk[l4>>1]
    //   hi int (j=4..7): src lane l15+32*(l4&1)+16, val pk[l4>>1]
    {
      const int sl = l15 + 32 * (l4 & 1);
      int v0a = __shfl(pk0, sl), v0b = __shfl(pk1, sl);
      int v1a = __shfl(pk0, sl + 16), v1b = __shfl(pk1, sl + 16);
      int vlo = (l4 & 2) ? v0b : v0a;
      int vhi = (l4 & 2) ? v1b : v1a;
      i64 a2 = (i64)((((unsigned long long)(unsigned)vhi) << 32) | (unsigned)vlo);

      // ---- GEMM2(ch): acc2 += T[16p x 32m] x w_out chunk; K=32 ----
      const unsigned char* W2 = Wsh2[b];
      #pragma unroll
      for (int ct = 0; ct < 16; ++ct) {
        i64 b2 = *(const i64*)&W2[ct * 512 + lane * 8];
        acc2[ct] = __builtin_amdgcn_mfma_f32_16x16x32_fp8_fp8(a2, b2, acc2[ct], 0, 0, 0);
      }
    }

    __syncthreads();  // buf flip: prefetch(ch+1) drained; all waves done with buf b
  }

  // ---- epilogue: out = x + gamma_c * (v + b_out_c) ----
  #pragma unroll
  for (int ct = 0; ct < 16; ++ct) {
    int cc = ct * 16 + l15;
    float gm = gamma[cc], bo = b_out[cc];
    int p = p0 + strip + l4 * 4;
    size_t off = xbase + (size_t)cc * HW + p;
    float4 xv = *(const float4*)(x + off);
    float4 o;
    #pragma unroll
    for (int r = 0; r < 4; ++r)
      ((float*)&o)[r] = ((const float*)&xv)[r] + gm * (acc2[ct][r] + bo);
    *(float4*)(out + off) = o;
  }
}

extern "C" void kernel_launch(void* const* d_in, const int* in_sizes, int n_in,
                              void* d_out, int out_size, void* d_ws, size_t ws_size,
                              hipStream_t stream) {
  const float* x = (const float*)d_in[0];
  const float* ln_w = (const float*)d_in[1];
  const float* ln_b = (const float*)d_in[2];
  const float* w_in = (const float*)d_in[3];
  const float* b_in = (const float*)d_in[4];
  const float* w_out = (const float*)d_in[5];
  const float* b_out = (const float*)d_in[6];
  const float* gamma = (const float*)d_in[7];
  float* out = (float*)d_out;

  char* ws = (char*)d_ws;
  unsigned char* w_in8p = (unsigned char*)ws;              // 256 KB frag-packed
  unsigned char* w_out8p = (unsigned char*)(ws + 262144);  // 256 KB frag-packed
  double* partial = (double*)(ws + 524288);                // 8 KB
  float* stats = (float*)(ws + 524288 + 8192);             // 512 B

  k_prep<<<512, 256, 0, stream>>>(w_in, w_out, w_in8p, w_out8p);
  k_stats1<<<512, 256, 0, stream>>>(x, partial);
  k_stats2<<<1, 64, 0, stream>>>(partial, stats);

  k_fused<<<1024, 512, 0, stream>>>(x, ln_w, ln_b, b_in, b_out, gamma,
                                    w_in8p, w_out8p, stats, out);
}

// Round 10
// 182.888 us; speedup vs baseline: 2.2909x; 1.0715x over previous
//
#include <hip/hip_runtime.h>
#include <math.h>

// x: (4,16,256,32,64) f32 -> NS=64 samples, CD=256 channels, HW=2048 positions
#define NS 64
#define CD 256
#define HW 2048
#define MD 1024
#define SAMPLE (CD * HW)
#define LN_EPS 1e-5f

#define PB 128           // positions per block (8 waves x 16-p strip)
#define MC 32            // m-chunk
#define NCH (MD / MC)    // 32 chunks

typedef float f32x4 __attribute__((ext_vector_type(4)));
typedef long i64;

// Rotated 4-bit XOR swizzle for Ysh (bits 3-6).
__device__ __forceinline__ int swz(int p) {
  int k = (p ^ (p >> 2)) & 15;
  return ((k & 7) << 4) | (k & 8);
}

__device__ __forceinline__ void gl_lds16(const unsigned char* g, unsigned char* l) {
  __builtin_amdgcn_global_load_lds(
      (const __attribute__((address_space(1))) unsigned char*)g,
      (__attribute__((address_space(3))) unsigned char*)l, 16, 0, 0);
}

// ---------------- weight prep: f32 -> fp8 e4m3, FRAGMENT-PACKED ----------------
// w_in8p[f*512 + l*8 + j]  = w_in[c,m], f=ch*16+mt*8+kk, m=ch*32+mt*16+(l&15),
//                            c=kk*32+(l>>4)*8+j
// w_out8p[g*512 + l*8 + j] = w_out[m,c], g=ch*16+ct, c=ct*16+(l&15),
//                            m=ch*32+(l>>4)*8+j
__global__ __launch_bounds__(256) void k_prep(const float* __restrict__ w_in,
                                              const float* __restrict__ w_out,
                                              unsigned char* __restrict__ w_in8p,
                                              unsigned char* __restrict__ w_out8p) {
  int id = blockIdx.x * 256 + threadIdx.x;  // 0..131071 (one int = 4 bytes each)
  if (id < 65536) {
    int i = id;
    int f = i >> 7, l = (i >> 1) & 63, j0 = (i & 1) * 4;
    int m = (f >> 3) * 16 + (l & 15);
    int c0 = (f & 7) * 32 + (l >> 4) * 8 + j0;
    float a = w_in[(size_t)(c0 + 0) * MD + m];
    float b = w_in[(size_t)(c0 + 1) * MD + m];
    float c = w_in[(size_t)(c0 + 2) * MD + m];
    float d = w_in[(size_t)(c0 + 3) * MD + m];
    int r = __builtin_amdgcn_cvt_pk_fp8_f32(a, b, 0, false);
    r = __builtin_amdgcn_cvt_pk_fp8_f32(c, d, r, true);
    ((int*)w_in8p)[i] = r;
  } else {
    int i = id - 65536;
    int g = i >> 7, l = (i >> 1) & 63, j0 = (i & 1) * 4;
    int c = (g & 15) * 16 + (l & 15);
    int m0 = (g >> 4) * 32 + (l >> 4) * 8 + j0;
    float a = w_out[(size_t)(m0 + 0) * CD + c];
    float b = w_out[(size_t)(m0 + 1) * CD + c];
    float cc = w_out[(size_t)(m0 + 2) * CD + c];
    float d = w_out[(size_t)(m0 + 3) * CD + c];
    int r = __builtin_amdgcn_cvt_pk_fp8_f32(a, b, 0, false);
    r = __builtin_amdgcn_cvt_pk_fp8_f32(cc, d, r, true);
    ((int*)w_out8p)[i] = r;
  }
}

// ---------------- LN stats, stage 1 ----------------
__global__ __launch_bounds__(256) void k_stats1(const float* __restrict__ x,
                                                double* __restrict__ partial) {
  int s = blockIdx.x >> 3, sl = blockIdx.x & 7;
  const float4* p = (const float4*)(x + (size_t)s * SAMPLE + (size_t)sl * 65536);
  double sum = 0.0, ssq = 0.0;
  for (int i = 0; i < 64; ++i) {
    float4 v = p[i * 256 + threadIdx.x];
    sum += (double)v.x + (double)v.y + (double)v.z + (double)v.w;
    ssq += (double)v.x * v.x + (double)v.y * v.y + (double)v.z * v.z + (double)v.w * v.w;
  }
  for (int off = 32; off; off >>= 1) {
    sum += __shfl_down(sum, off);
    ssq += __shfl_down(ssq, off);
  }
  __shared__ double red[4][2];
  int wv = threadIdx.x >> 6, ln = threadIdx.x & 63;
  if (ln == 0) { red[wv][0] = sum; red[wv][1] = ssq; }
  __syncthreads();
  if (threadIdx.x == 0) {
    for (int i = 1; i < 4; ++i) { sum += red[i][0]; ssq += red[i][1]; }
    partial[blockIdx.x * 2] = sum;
    partial[blockIdx.x * 2 + 1] = ssq;
  }
}

// ---------------- LN stats, stage 2 ----------------
__global__ void k_stats2(const double* __restrict__ partial, float* __restrict__ stats) {
  int s = threadIdx.x;  // 64 threads
  double sum = 0.0, ssq = 0.0;
  for (int i = 0; i < 8; ++i) {
    sum += partial[(s * 8 + i) * 2];
    ssq += partial[(s * 8 + i) * 2 + 1];
  }
  double mean = sum / (double)SAMPLE;
  double var = ssq / (double)SAMPLE - mean * mean;
  stats[s * 2] = (float)mean;
  stats[s * 2 + 1] = (float)(1.0 / sqrt(var + (double)LN_EPS));
}

// ---------------- fused LN + MLP + layer-scale + residual ----------------
// r9 structure + deferred-GEMM2 pipeline: each iteration opens with 32
// INDEPENDENT MFMAs (GEMM2(ch-1) into acc2 + GEMM1(ch)), and the serial
// GELU+shfl tail produces a2_prev consumed only NEXT iteration -> its latency
// hides under the barrier + next MFMA burst. Cross-chunk state = 1 i64 (no
// r4-style reg batches -> no spill). Wsh2 triple-buffered (write (ch+1)%3,
// read (ch-1)%3, hold ch%3 -- pairwise distinct). setprio(1) around the MFMA
// cluster (T5; role diversity now exists). LDS 72KB dynamic, 2 blocks/CU.
__global__ __launch_bounds__(512, 4) void k_fused(
    const float* __restrict__ x, const float* __restrict__ ln_w, const float* __restrict__ ln_b,
    const float* __restrict__ b_in, const float* __restrict__ b_out, const float* __restrict__ gamma,
    const unsigned char* __restrict__ w_in8p, const unsigned char* __restrict__ w_out8p,
    const float* __restrict__ stats, float* __restrict__ out) {
  extern __shared__ unsigned char smem[];
  unsigned char* Ysh = smem;              // [128][256] fp8 swizzled, 32KB
  unsigned char* Wsh1 = smem + 32768;     // [2][8192] a-frags dbuf
  unsigned char* Wsh2 = smem + 49152;     // [3][8192] b2-frags triple-buf

  const int tid = threadIdx.x;
  const int lane = tid & 63, l15 = lane & 15, l4 = lane >> 4;
  const int wv = tid >> 6;                 // 0..7
  const int s = blockIdx.x >> 4;
  const int p0 = (blockIdx.x & 15) * PB;
  const float mu = stats[s * 2], rstd = stats[s * 2 + 1];
  const float a_ln = rstd, c_ln = -mu * rstd;
  const size_t xbase = (size_t)s * SAMPLE;

  // ---- prefetch chunk 0 weights (hides under Ysh staging) ----
  gl_lds16(w_in8p + wv * 1024 + lane * 16, Wsh1 + wv * 1024);
  gl_lds16(w_out8p + wv * 1024 + lane * 16, Wsh2 + wv * 1024);

  // ---- stage Ysh: normalize + affine, transpose (c,p)->(p,c), cvt fp8 ----
  #pragma unroll
  for (int it = 0; it < 4; ++it) {
    int bid = it * 512 + tid;               // 2048 4x4 micro-blocks
    int c0 = (bid >> 5) * 4, pp = (bid & 31) * 4;
    float yv[4][4];
    #pragma unroll
    for (int i = 0; i < 4; ++i) {
      size_t off = (size_t)(c0 + i) * HW + p0 + pp;
      float4 xv = *(const float4*)(x + xbase + off);
      float4 lw = *(const float4*)(ln_w + off);
      float4 lb = *(const float4*)(ln_b + off);
      yv[i][0] = fmaf(fmaf(xv.x, a_ln, c_ln), lw.x, lb.x);
      yv[i][1] = fmaf(fmaf(xv.y, a_ln, c_ln), lw.y, lb.y);
      yv[i][2] = fmaf(fmaf(xv.z, a_ln, c_ln), lw.z, lb.z);
      yv[i][3] = fmaf(fmaf(xv.w, a_ln, c_ln), lw.w, lb.w);
    }
    #pragma unroll
    for (int j = 0; j < 4; ++j) {
      int p = pp + j;
      int r = __builtin_amdgcn_cvt_pk_fp8_f32(yv[0][j], yv[1][j], 0, false);
      r = __builtin_amdgcn_cvt_pk_fp8_f32(yv[2][j], yv[3][j], r, true);
      *(int*)&Ysh[p * 256 + (c0 ^ swz(p))] = r;
    }
  }

  const int strip = wv * 16;               // wave's p-strip
  const int pY = strip + l15;              // Ysh row this lane reads
  const int sY = swz(pY);
  f32x4 acc2[16] = {};                     // 16p x 256c per wave (16 c-tiles)

  __syncthreads();  // Ysh ready + chunk-0 weights drained

  // ---- breg: chunk-invariant Ysh B-frags -> 8 i64 registers ----
  i64 breg[8];
  #pragma unroll
  for (int kk = 0; kk < 8; ++kk)
    breg[kk] = *(const i64*)&Ysh[pY * 256 + ((kk * 32 + l4 * 8) ^ sY)];

  i64 a2_prev = 0;

  for (int ch = 0; ch < NCH; ++ch) {
    if (ch) __syncthreads();  // Wsh*[ch] arrived; everyone done with old slots

    // ---- prefetch chunk ch+1 (slots distinct from reads this iter) ----
    if (ch + 1 < NCH) {
      const size_t co = (size_t)(ch + 1) * 8192;
      gl_lds16(w_in8p + co + wv * 1024 + lane * 16,
               Wsh1 + ((ch + 1) & 1) * 8192 + wv * 1024);
      gl_lds16(w_out8p + co + wv * 1024 + lane * 16,
               Wsh2 + ((ch + 1) % 3) * 8192 + wv * 1024);
    }

    __builtin_amdgcn_s_setprio(1);
    // ---- GEMM2(ch-1): 16 independent MFMAs, no serial deps ----
    if (ch) {
      const unsigned char* W2 = Wsh2 + ((ch - 1) % 3) * 8192;
      #pragma unroll
      for (int ct = 0; ct < 16; ++ct) {
        i64 b2 = *(const i64*)&W2[ct * 512 + lane * 8];
        acc2[ct] = __builtin_amdgcn_mfma_f32_16x16x32_fp8_fp8(a2_prev, b2, acc2[ct], 0, 0, 0);
      }
    }

    // ---- GEMM1(ch): D1[32m x 16p], K=256 ----
    const unsigned char* W1 = Wsh1 + (ch & 1) * 8192;
    f32x4 acc1[2] = {};
    #pragma unroll
    for (int kk = 0; kk < 8; ++kk) {
      i64 a0 = *(const i64*)&W1[(kk)*512 + lane * 8];
      i64 a1 = *(const i64*)&W1[(8 + kk) * 512 + lane * 8];
      acc1[0] = __builtin_amdgcn_mfma_f32_16x16x32_fp8_fp8(a0, breg[kk], acc1[0], 0, 0, 0);
      acc1[1] = __builtin_amdgcn_mfma_f32_16x16x32_fp8_fp8(a1, breg[kk], acc1[1], 0, 0, 0);
    }
    __builtin_amdgcn_s_setprio(0);

    // ---- GELU -> packed fp8 ints (tail; consumed only next iteration) ----
    int pk0, pk1;
    #pragma unroll
    for (int mt = 0; mt < 2; ++mt) {
      const float4 bi = *(const float4*)&b_in[ch * 32 + mt * 16 + l4 * 4];
      float g[4];
      #pragma unroll
      for (int r = 0; r < 4; ++r) {
        float t = acc1[mt][r] + ((const float*)&bi)[r];
        g[r] = t * __builtin_amdgcn_rcpf(1.0f + __expf(-1.702f * t));
      }
      int pk = __builtin_amdgcn_cvt_pk_fp8_f32(g[0], g[1], 0, false);
      pk = __builtin_amdgcn_cvt_pk_fp8_f32(g[2], g[3], pk, true);
      if (mt == 0) pk0 = pk; else pk1 = pk;
    }

    // ---- in-register transpose to GEMM2 A-frag layout (4 shfl) ----
    // writer lane (l15,l4w) holds pk_mt = T[p=strip+l15][m=mt*16+l4w*4..+3];
    // reader lane (l15,l4) needs m = 8*l4+j:
    //   lo int: src lane l15+32*(l4&1), val pk[l4>>1]; hi int: src +16.
    {
      const int sl = l15 + 32 * (l4 & 1);
      int v0a = __shfl(pk0, sl), v0b = __shfl(pk1, sl);
      int v1a = __shfl(pk0, sl + 16), v1b = __shfl(pk1, sl + 16);
      int vlo = (l4 & 2) ? v0b : v0a;
      int vhi = (l4 & 2) ? v1b : v1a;
      a2_prev = (i64)((((unsigned long long)(unsigned)vhi) << 32) | (unsigned)vlo);
    }
  }

  // ---- drain GEMM2 for last chunk (slot (NCH-1)%3 intact, no barrier needed) ----
  {
    const unsigned char* W2 = Wsh2 + ((NCH - 1) % 3) * 8192;
    #pragma unroll
    for (int ct = 0; ct < 16; ++ct) {
      i64 b2 = *(const i64*)&W2[ct * 512 + lane * 8];
      acc2[ct] = __builtin_amdgcn_mfma_f32_16x16x32_fp8_fp8(a2_prev, b2, acc2[ct], 0, 0, 0);
    }
  }

  // ---- epilogue: out = x + gamma_c * (v + b_out_c) ----
  #pragma unroll
  for (int ct = 0; ct < 16; ++ct) {
    int cc = ct * 16 + l15;
    float gm = gamma[cc], bo = b_out[cc];
    int p = p0 + strip + l4 * 4;
    size_t off = xbase + (size_t)cc * HW + p;
    float4 xv = *(const float4*)(x + off);
    float4 o;
    #pragma unroll
    for (int r = 0; r < 4; ++r)
      ((float*)&o)[r] = ((const float*)&xv)[r] + gm * (acc2[ct][r] + bo);
    *(float4*)(out + off) = o;
  }
}

extern "C" void kernel_launch(void* const* d_in, const int* in_sizes, int n_in,
                              void* d_out, int out_size, void* d_ws, size_t ws_size,
                              hipStream_t stream) {
  const float* x = (const float*)d_in[0];
  const float* ln_w = (const float*)d_in[1];
  const float* ln_b = (const float*)d_in[2];
  const float* w_in = (const float*)d_in[3];
  const float* b_in = (const float*)d_in[4];
  const float* w_out = (const float*)d_in[5];
  const float* b_out = (const float*)d_in[6];
  const float* gamma = (const float*)d_in[7];
  float* out = (float*)d_out;

  char* ws = (char*)d_ws;
  unsigned char* w_in8p = (unsigned char*)ws;              // 256 KB frag-packed
  unsigned char* w_out8p = (unsigned char*)(ws + 262144);  // 256 KB frag-packed
  double* partial = (double*)(ws + 524288);                // 8 KB
  float* stats = (float*)(ws + 524288 + 8192);             // 512 B

  k_prep<<<512, 256, 0, stream>>>(w_in, w_out, w_in8p, w_out8p);
  k_stats1<<<512, 256, 0, stream>>>(x, partial);
  k_stats2<<<1, 64, 0, stream>>>(partial, stats);

  const int lds_bytes = 32768 + 16384 + 24576;  // 73728
  hipFuncSetAttribute((const void*)k_fused, hipFuncAttributeMaxDynamicSharedMemorySize,
                      lds_bytes);
  k_fused<<<1024, 512, lds_bytes, stream>>>(x, ln_w, ln_b, b_in, b_out, gamma,
                                            w_in8p, w_out8p, stats, out);
}